// Round 7
// baseline (1006.665 us; speedup 1.0000x reference)
//
#include <hip/hip_runtime.h>
#include <hip/hip_bf16.h>
#include <cstdint>
#include <cstddef>

#define S_LEN 2048
#define DM 1024
#define NEGV -1.0e9f

typedef __attribute__((ext_vector_type(8))) short bf16x8;
typedef __attribute__((ext_vector_type(4))) float f32x4;
typedef __attribute__((ext_vector_type(4))) unsigned short us4;
typedef __attribute__((ext_vector_type(4))) int i32x4;
typedef __attribute__((ext_vector_type(2))) unsigned int u32x2;

__device__ __forceinline__ unsigned short f2bf(float f) {
  unsigned int u = __float_as_uint(f);
  unsigned int r = (u + 0x7fffu + ((u >> 16) & 1u)) >> 16;
  return (unsigned short)r;
}

__device__ __forceinline__ unsigned int pack_bf2(float a, float b) {
  return (unsigned int)f2bf(a) | ((unsigned int)f2bf(b) << 16);
}

__device__ __forceinline__ void async_copy16(const void* g, void* l) {
  __builtin_amdgcn_global_load_lds((const __attribute__((address_space(1))) void*)g,
                                   (__attribute__((address_space(3))) void*)l, 16, 0, 0);
}

// ---------------- f32 -> bf16 convert ----------------
__global__ void cvt_kernel(const float* __restrict__ src, unsigned short* __restrict__ dst, int n4) {
  int i = blockIdx.x * blockDim.x + threadIdx.x;
  if (i >= n4) return;
  const float4 v = reinterpret_cast<const float4*>(src)[i];
  us4 o;
  o[0] = f2bf(v.x); o[1] = f2bf(v.y); o[2] = f2bf(v.z); o[3] = f2bf(v.w);
  reinterpret_cast<us4*>(dst)[i] = o;
}

// ---------------- projection GEMM (unchanged, passed) ----------------
__global__ __launch_bounds__(256) void proj_gemm(
    const unsigned short* __restrict__ Xq, const unsigned short* __restrict__ Wqw,
    const float* __restrict__ bq, unsigned short* __restrict__ Cq,
    const unsigned short* __restrict__ Xk, const unsigned short* __restrict__ Wkw,
    const float* __restrict__ bk, unsigned short* __restrict__ Ck,
    const unsigned short* __restrict__ Xv, const unsigned short* __restrict__ Wvw,
    const float* __restrict__ bv, unsigned short* __restrict__ Cv) {
  const unsigned short* X; const unsigned short* W; const float* bias; unsigned short* C;
  if (blockIdx.z == 0)      { X = Xq; W = Wqw; bias = bq; C = Cq; }
  else if (blockIdx.z == 1) { X = Xk; W = Wkw; bias = bk; C = Ck; }
  else                      { X = Xv; W = Wvw; bias = bv; C = Cv; }

  __shared__ unsigned short Ab[128 * 64];
  __shared__ unsigned short Bb[128 * 64];

  const int t  = threadIdx.x;
  const int wv = t >> 6, l = t & 63;
  const int lr = l & 15, lg = l >> 4;
  const int wr = wv >> 1, wc = wv & 1;
  const int m0 = blockIdx.y * 128, n0 = blockIdx.x * 128;

  const f32x4 fz = {0.f, 0.f, 0.f, 0.f};
  f32x4 acc[4][4];
#pragma unroll
  for (int m = 0; m < 4; ++m)
#pragma unroll
    for (int n = 0; n < 4; ++n) acc[m][n] = fz;

  const int srow = t >> 3;
  const int sc16 = t & 7;

  for (int kt = 0; kt < 16; ++kt) {
    const int kb = kt * 64;
#pragma unroll
    for (int it = 0; it < 4; ++it) {
      const int row = it * 32 + srow;
      const int c16 = sc16 ^ (row & 7);
      const unsigned short* gA = X + (size_t)(m0 + row) * DM + kb + c16 * 8;
      const unsigned short* gB = W + (size_t)(n0 + row) * DM + kb + c16 * 8;
      async_copy16(gA, (char*)Ab + it * 4096 + wv * 1024);
      async_copy16(gB, (char*)Bb + it * 4096 + wv * 1024);
    }
    __syncthreads();
#pragma unroll
    for (int kk = 0; kk < 2; ++kk) {
      bf16x8 af[4], bfr[4];
      const int c16 = kk * 4 + lg;
      const int sw = (c16 ^ (lr & 7)) * 16;
#pragma unroll
      for (int m = 0; m < 4; ++m) {
        const int row = wr * 64 + m * 16 + lr;
        af[m] = *(const bf16x8*)((const char*)Ab + row * 128 + sw);
      }
#pragma unroll
      for (int n = 0; n < 4; ++n) {
        const int row = wc * 64 + n * 16 + lr;
        bfr[n] = *(const bf16x8*)((const char*)Bb + row * 128 + sw);
      }
#pragma unroll
      for (int m = 0; m < 4; ++m)
#pragma unroll
        for (int n = 0; n < 4; ++n)
          acc[m][n] = __builtin_amdgcn_mfma_f32_16x16x32_bf16(af[m], bfr[n], acc[m][n], 0, 0, 0);
    }
    __syncthreads();
  }

#pragma unroll
  for (int n = 0; n < 4; ++n) {
    const int ccol = n0 + wc * 64 + n * 16 + lr;
    const float bb = bias[ccol];
#pragma unroll
    for (int m = 0; m < 4; ++m) {
      const int crow0 = m0 + wr * 64 + m * 16 + lg * 4;
#pragma unroll
      for (int j = 0; j < 4; ++j)
        C[(size_t)(crow0 + j) * DM + ccol] = f2bf(acc[m][n][j] + bb);
    }
  }
}

// ---------------- V transpose: [4096,1024] -> [1024,4096] ----------------
__global__ void transpose_bf(const unsigned short* __restrict__ src, unsigned short* __restrict__ dst) {
  __shared__ unsigned short tb[32][33];
  const int x = threadIdx.x & 31, y = threadIdx.x >> 5;
  const int bx = blockIdx.x, by = blockIdx.y;
#pragma unroll
  for (int r = 0; r < 32; r += 8)
    tb[r + y][x] = src[(size_t)(by * 32 + r + y) * DM + bx * 32 + x];
  __syncthreads();
#pragma unroll
  for (int r = 0; r < 32; r += 8)
    dst[(size_t)(bx * 32 + r + y) * 4096 + by * 32 + x] = tb[x][r + y];
}

// ---------------- fused attention v6: occupancy x2 + zero-VALU LDS repack ----------------
// vs v5: (1) per-wave union of P-repack buffer with out-reduction buffer ->
// LDS 53.8->33.3 KB -> 4 blocks/CU (32 waves/CU, was 16); (2) LDS gets the raw
// packed bf16 exp registers (bit-copy, no unpack/repack VALU); rinv folded into
// the output epilogue (PV is linear). attn stores still apply rinv (required).
__global__ __launch_bounds__(512, 8) void attn6_kernel(
    const unsigned short* __restrict__ Qp, const unsigned short* __restrict__ Kp,
    const unsigned short* __restrict__ Vt, const int* __restrict__ mask,
    float* __restrict__ outp, float* __restrict__ attnp) {
  __shared__ float rsred[8][16];                      // 512 B
  __shared__ char uni[8][4096];                       // 32 KB: per-wave Pb (2x16x40 sh) U outred (16x64 f32)

  const int bx = blockIdx.x;
  const int c  = bx & 7;            // XCD (round-robin dispatch)
  const int s  = bx >> 3;           // temporal order within XCD
  const int j  = s & 3;             // which of this XCD's 4 (b,h) pairs
  const int qt = s >> 2;            // 0..127, outer
  const int bh = c * 4 + j;
  const int b  = bh >> 4, h = bh & 15;
  const int q0 = qt << 4;

  const int w = threadIdx.x >> 6, l = threadIdx.x & 63;
  const int lr = l & 15, lg = l >> 4;
  const int kw0 = w << 8;                      // 256 keys per wave

  const float scale = 0.125f;
  const f32x4 fz = {0.f, 0.f, 0.f, 0.f};

  // Q as B-operand: lane holds Q[q0+lr][lg*8..+7]
  const unsigned short* Qh = Qp + (size_t)(b * S_LEN + q0 + lr) * DM + h * 64;
  const bf16x8 qf0 = *(const bf16x8*)(Qh + lg * 8);
  const bf16x8 qf1 = *(const bf16x8*)(Qh + 32 + lg * 8);

  const unsigned short* Kh = Kp + (size_t)b * S_LEN * DM + h * 64 + (size_t)kw0 * DM;
  const int* mrow = mask + (size_t)(b * S_LEN + q0 + lr) * S_LEN + kw0;

  // ---- QK^T + mask + exp (one pass over K), packed bf16 in regs ----
  unsigned int pkA[16], pkB[16];
  float rs = 0.f;
#pragma unroll
  for (int i = 0; i < 16; ++i) {
    const unsigned short* Kr = Kh + (size_t)(i * 16 + lr) * DM;
    const bf16x8 ka0 = *(const bf16x8*)(Kr + lg * 8);
    const bf16x8 ka1 = *(const bf16x8*)(Kr + 32 + lg * 8);
    const i32x4 m4 = *(const i32x4*)(mrow + i * 16 + lg * 4);
    f32x4 sc = fz;
    sc = __builtin_amdgcn_mfma_f32_16x16x32_bf16(ka0, qf0, sc, 0, 0, 0);
    sc = __builtin_amdgcn_mfma_f32_16x16x32_bf16(ka1, qf1, sc, 0, 0, 0);
    const float e0 = __expf((m4[0] == 0) ? NEGV : sc[0] * scale);
    const float e1 = __expf((m4[1] == 0) ? NEGV : sc[1] * scale);
    const float e2 = __expf((m4[2] == 0) ? NEGV : sc[2] * scale);
    const float e3 = __expf((m4[3] == 0) ? NEGV : sc[3] * scale);
    rs += (e0 + e1) + (e2 + e3);
    pkA[i] = pack_bf2(e0, e1);
    pkB[i] = pack_bf2(e2, e3);
  }
  // per-wave row sum for q=lr (4 lanes with same lr hold partials)
  rs += __shfl_xor(rs, 16, 64);
  rs += __shfl_xor(rs, 32, 64);
  if (l < 16) rsred[w][l] = rs;
  __syncthreads();
  float ssum = 0.f;
#pragma unroll
  for (int ww = 0; ww < 8; ++ww) ssum += rsred[ww][lr];
  const float rinv = 1.0f / ssum;

  // ---- attn store (normalized) + PV on unnormalized P ----
  float* attnq = attnp + (size_t)((b * 16 + h) * S_LEN + q0 + lr) * S_LEN + kw0;
  const unsigned short* Vh = Vt + (size_t)(h * 64) * (2 * S_LEN) + (size_t)b * S_LEN + kw0;
  unsigned short* pbase = (unsigned short*)uni[w];

  f32x4 oacc[4];
#pragma unroll
  for (int n = 0; n < 4; ++n) oacc[n] = fz;

#pragma unroll
  for (int win = 0; win < 8; ++win) {
    const int wb = win * 32;
    const unsigned int a0 = pkA[2 * win],     a1 = pkB[2 * win];
    const unsigned int b0 = pkA[2 * win + 1], b1 = pkB[2 * win + 1];
    // normalized attn store (unpack bf16 halves + one mul each)
    const f32x4 st0 = {__uint_as_float(a0 << 16) * rinv,
                       __uint_as_float(a0 & 0xffff0000u) * rinv,
                       __uint_as_float(a1 << 16) * rinv,
                       __uint_as_float(a1 & 0xffff0000u) * rinv};
    const f32x4 st1 = {__uint_as_float(b0 << 16) * rinv,
                       __uint_as_float(b0 & 0xffff0000u) * rinv,
                       __uint_as_float(b1 << 16) * rinv,
                       __uint_as_float(b1 & 0xffff0000u) * rinv};
    __builtin_nontemporal_store(st0, (f32x4*)(attnq + wb + lg * 4));
    __builtin_nontemporal_store(st1, (f32x4*)(attnq + wb + 16 + lg * 4));

    // wave-private LDS repack: raw packed bf16 (zero VALU), double-buffered
    unsigned short* pb = pbase + (win & 1) * 640;
    const u32x2 wv0 = {a0, a1};
    const u32x2 wv1 = {b0, b1};
    *(u32x2*)(pb + lr * 40 + lg * 4) = wv0;
    *(u32x2*)(pb + lr * 40 + 16 + lg * 4) = wv1;
    const bf16x8 pa = *(const bf16x8*)(pb + lr * 40 + lg * 8);  // A[q=lr][k=lg*8..+7]

#pragma unroll
    for (int n = 0; n < 4; ++n) {
      const bf16x8 vb = *(const bf16x8*)(Vh + (size_t)(n * 16 + lr) * (2 * S_LEN) + wb + lg * 8);
      oacc[n] = __builtin_amdgcn_mfma_f32_16x16x32_bf16(pa, vb, oacc[n], 0, 0, 0);
    }
  }

  // ---- cross-wave out reduction (unnormalized; rinv applied per q-row here) ----
  asm volatile("s_waitcnt lgkmcnt(0)" ::: "memory");  // Pb reads done before outred overwrite
  float* outred = (float*)uni[w];
#pragma unroll
  for (int n = 0; n < 4; ++n)
#pragma unroll
    for (int jj = 0; jj < 4; ++jj)
      outred[(lg * 4 + jj) * 64 + n * 16 + lr] = oacc[n][jj];
  __syncthreads();
  if (threadIdx.x < 256) {
    const int q = threadIdx.x >> 4;
    const int d0 = (threadIdx.x & 15) * 4;
    float sq = 0.f;
#pragma unroll
    for (int ww = 0; ww < 8; ++ww) sq += rsred[ww][q];
    const float rq = 1.0f / sq;
    float4 o = {0.f, 0.f, 0.f, 0.f};
#pragma unroll
    for (int ww = 0; ww < 8; ++ww) {
      const f32x4 sv = *(const f32x4*)((const float*)uni[ww] + q * 64 + d0);
      o.x += sv[0]; o.y += sv[1]; o.z += sv[2]; o.w += sv[3];
    }
    o.x *= rq; o.y *= rq; o.z *= rq; o.w *= rq;
    *(float4*)(outp + (size_t)(b * S_LEN + q0 + q) * DM + h * 64 + d0) = o;
  }
}

extern "C" void kernel_launch(void* const* d_in, const int* in_sizes, int n_in,
                              void* d_out, int out_size, void* d_ws, size_t ws_size,
                              hipStream_t stream) {
  const float* query = (const float*)d_in[0];
  const float* key_  = (const float*)d_in[1];
  const float* value = (const float*)d_in[2];
  const int*   mask  = (const int*)d_in[3];
  const float* Wq = (const float*)d_in[4];
  const float* bq = (const float*)d_in[5];
  const float* Wk = (const float*)d_in[6];
  const float* bk = (const float*)d_in[7];
  const float* Wv = (const float*)d_in[8];
  const float* bv = (const float*)d_in[9];

  float* outp  = (float*)d_out;
  float* attnp = outp + (size_t)2 * S_LEN * DM;

  unsigned short* ws  = (unsigned short*)d_ws;
  unsigned short* qbf = ws;
  unsigned short* kbf = qbf + 4194304;
  unsigned short* vbf = kbf + 4194304;
  unsigned short* wqb = vbf + 4194304;
  unsigned short* wkb = wqb + 1048576;
  unsigned short* wvb = wkb + 1048576;
  unsigned short* qp  = wvb + 1048576;
  unsigned short* kp  = qp + 4194304;
  unsigned short* vp  = kp + 4194304;
  unsigned short* vt  = vp + 4194304;

  cvt_kernel<<<4096, 256, 0, stream>>>(query, qbf, 1048576);
  cvt_kernel<<<4096, 256, 0, stream>>>(key_,  kbf, 1048576);
  cvt_kernel<<<4096, 256, 0, stream>>>(value, vbf, 1048576);
  cvt_kernel<<<1024, 256, 0, stream>>>(Wq, wqb, 262144);
  cvt_kernel<<<1024, 256, 0, stream>>>(Wk, wkb, 262144);
  cvt_kernel<<<1024, 256, 0, stream>>>(Wv, wvb, 262144);

  proj_gemm<<<dim3(8, 32, 3), 256, 0, stream>>>(qbf, wqb, bq, qp,
                                                kbf, wkb, bk, kp,
                                                vbf, wvb, bv, vp);
  transpose_bf<<<dim3(32, 128), 256, 0, stream>>>(vp, vt);
  attn6_kernel<<<4096, 512, 0, stream>>>(qp, kp, vt, mask, outp, attnp);
}

// Round 8
// 418.845 us; speedup vs baseline: 2.4034x; 2.4034x over previous
//
#include <hip/hip_runtime.h>
#include <hip/hip_bf16.h>
#include <cstdint>
#include <cstddef>

#define S_LEN 2048
#define DM 1024
#define NEGV -1.0e9f

typedef __attribute__((ext_vector_type(8))) short bf16x8;
typedef __attribute__((ext_vector_type(4))) float f32x4;
typedef __attribute__((ext_vector_type(4))) unsigned short us4;
typedef __attribute__((ext_vector_type(4))) int i32x4;
typedef __attribute__((ext_vector_type(2))) unsigned int u32x2;

__device__ __forceinline__ unsigned short f2bf(float f) {
  unsigned int u = __float_as_uint(f);
  unsigned int r = (u + 0x7fffu + ((u >> 16) & 1u)) >> 16;
  return (unsigned short)r;
}

__device__ __forceinline__ unsigned int pack_bf2(float a, float b) {
  return (unsigned int)f2bf(a) | ((unsigned int)f2bf(b) << 16);
}

__device__ __forceinline__ void async_copy16(const void* g, void* l) {
  __builtin_amdgcn_global_load_lds((const __attribute__((address_space(1))) void*)g,
                                   (__attribute__((address_space(3))) void*)l, 16, 0, 0);
}

// ---------------- f32 -> bf16 convert ----------------
__global__ void cvt_kernel(const float* __restrict__ src, unsigned short* __restrict__ dst, int n4) {
  int i = blockIdx.x * blockDim.x + threadIdx.x;
  if (i >= n4) return;
  const float4 v = reinterpret_cast<const float4*>(src)[i];
  us4 o;
  o[0] = f2bf(v.x); o[1] = f2bf(v.y); o[2] = f2bf(v.z); o[3] = f2bf(v.w);
  reinterpret_cast<us4*>(dst)[i] = o;
}

// ---------------- projection GEMM (unchanged, passed) ----------------
__global__ __launch_bounds__(256) void proj_gemm(
    const unsigned short* __restrict__ Xq, const unsigned short* __restrict__ Wqw,
    const float* __restrict__ bq, unsigned short* __restrict__ Cq,
    const unsigned short* __restrict__ Xk, const unsigned short* __restrict__ Wkw,
    const float* __restrict__ bk, unsigned short* __restrict__ Ck,
    const unsigned short* __restrict__ Xv, const unsigned short* __restrict__ Wvw,
    const float* __restrict__ bv, unsigned short* __restrict__ Cv) {
  const unsigned short* X; const unsigned short* W; const float* bias; unsigned short* C;
  if (blockIdx.z == 0)      { X = Xq; W = Wqw; bias = bq; C = Cq; }
  else if (blockIdx.z == 1) { X = Xk; W = Wkw; bias = bk; C = Ck; }
  else                      { X = Xv; W = Wvw; bias = bv; C = Cv; }

  __shared__ unsigned short Ab[128 * 64];
  __shared__ unsigned short Bb[128 * 64];

  const int t  = threadIdx.x;
  const int wv = t >> 6, l = t & 63;
  const int lr = l & 15, lg = l >> 4;
  const int wr = wv >> 1, wc = wv & 1;
  const int m0 = blockIdx.y * 128, n0 = blockIdx.x * 128;

  const f32x4 fz = {0.f, 0.f, 0.f, 0.f};
  f32x4 acc[4][4];
#pragma unroll
  for (int m = 0; m < 4; ++m)
#pragma unroll
    for (int n = 0; n < 4; ++n) acc[m][n] = fz;

  const int srow = t >> 3;
  const int sc16 = t & 7;

  for (int kt = 0; kt < 16; ++kt) {
    const int kb = kt * 64;
#pragma unroll
    for (int it = 0; it < 4; ++it) {
      const int row = it * 32 + srow;
      const int c16 = sc16 ^ (row & 7);
      const unsigned short* gA = X + (size_t)(m0 + row) * DM + kb + c16 * 8;
      const unsigned short* gB = W + (size_t)(n0 + row) * DM + kb + c16 * 8;
      async_copy16(gA, (char*)Ab + it * 4096 + wv * 1024);
      async_copy16(gB, (char*)Bb + it * 4096 + wv * 1024);
    }
    __syncthreads();
#pragma unroll
    for (int kk = 0; kk < 2; ++kk) {
      bf16x8 af[4], bfr[4];
      const int c16 = kk * 4 + lg;
      const int sw = (c16 ^ (lr & 7)) * 16;
#pragma unroll
      for (int m = 0; m < 4; ++m) {
        const int row = wr * 64 + m * 16 + lr;
        af[m] = *(const bf16x8*)((const char*)Ab + row * 128 + sw);
      }
#pragma unroll
      for (int n = 0; n < 4; ++n) {
        const int row = wc * 64 + n * 16 + lr;
        bfr[n] = *(const bf16x8*)((const char*)Bb + row * 128 + sw);
      }
#pragma unroll
      for (int m = 0; m < 4; ++m)
#pragma unroll
        for (int n = 0; n < 4; ++n)
          acc[m][n] = __builtin_amdgcn_mfma_f32_16x16x32_bf16(af[m], bfr[n], acc[m][n], 0, 0, 0);
    }
    __syncthreads();
  }

#pragma unroll
  for (int n = 0; n < 4; ++n) {
    const int ccol = n0 + wc * 64 + n * 16 + lr;
    const float bb = bias[ccol];
#pragma unroll
    for (int m = 0; m < 4; ++m) {
      const int crow0 = m0 + wr * 64 + m * 16 + lg * 4;
#pragma unroll
      for (int j = 0; j < 4; ++j)
        C[(size_t)(crow0 + j) * DM + ccol] = f2bf(acc[m][n][j] + bb);
    }
  }
}

// ---------------- V transpose: [4096,1024] -> [1024,4096] ----------------
__global__ void transpose_bf(const unsigned short* __restrict__ src, unsigned short* __restrict__ dst) {
  __shared__ unsigned short tb[32][33];
  const int x = threadIdx.x & 31, y = threadIdx.x >> 5;
  const int bx = blockIdx.x, by = blockIdx.y;
#pragma unroll
  for (int r = 0; r < 32; r += 8)
    tb[r + y][x] = src[(size_t)(by * 32 + r + y) * DM + bx * 32 + x];
  __syncthreads();
#pragma unroll
  for (int r = 0; r < 32; r += 8)
    dst[(size_t)(bx * 32 + r + y) * 4096 + by * 32 + x] = tb[x][r + y];
}

// ---------------- fused attention v7: v6 structure, sane register budget ----------------
// vs v6: __launch_bounds__(512,4) — the (512,8) pin capped VGPR at 64 and spilled
// pk to scratch (1.4 GB of spill traffic). LDS 33.3 KB already allows 4 blocks/CU;
// at ~64-90 VGPR the RF also allows 8 waves/SIMD, so occupancy target is unchanged.
__global__ __launch_bounds__(512, 4) void attn7_kernel(
    const unsigned short* __restrict__ Qp, const unsigned short* __restrict__ Kp,
    const unsigned short* __restrict__ Vt, const int* __restrict__ mask,
    float* __restrict__ outp, float* __restrict__ attnp) {
  __shared__ float rsred[8][16];                      // 512 B
  __shared__ char uni[8][4096];                       // 32 KB: per-wave Pb (2x640 sh) U outred (16x64 f32)

  const int bx = blockIdx.x;
  const int c  = bx & 7;            // XCD (round-robin dispatch)
  const int s  = bx >> 3;           // temporal order within XCD
  const int j  = s & 3;             // which of this XCD's 4 (b,h) pairs
  const int qt = s >> 2;            // 0..127, outer
  const int bh = c * 4 + j;
  const int b  = bh >> 4, h = bh & 15;
  const int q0 = qt << 4;

  const int w = threadIdx.x >> 6, l = threadIdx.x & 63;
  const int lr = l & 15, lg = l >> 4;
  const int kw0 = w << 8;                      // 256 keys per wave

  const float scale = 0.125f;
  const f32x4 fz = {0.f, 0.f, 0.f, 0.f};

  // Q as B-operand: lane holds Q[q0+lr][lg*8..+7]
  const unsigned short* Qh = Qp + (size_t)(b * S_LEN + q0 + lr) * DM + h * 64;
  const bf16x8 qf0 = *(const bf16x8*)(Qh + lg * 8);
  const bf16x8 qf1 = *(const bf16x8*)(Qh + 32 + lg * 8);

  const unsigned short* Kh = Kp + (size_t)b * S_LEN * DM + h * 64 + (size_t)kw0 * DM;
  const int* mrow = mask + (size_t)(b * S_LEN + q0 + lr) * S_LEN + kw0;

  // ---- QK^T + mask + exp (one pass over K), packed bf16 in regs ----
  unsigned int pkA[16], pkB[16];
  float rs = 0.f;
#pragma unroll
  for (int i = 0; i < 16; ++i) {
    const unsigned short* Kr = Kh + (size_t)(i * 16 + lr) * DM;
    const bf16x8 ka0 = *(const bf16x8*)(Kr + lg * 8);
    const bf16x8 ka1 = *(const bf16x8*)(Kr + 32 + lg * 8);
    const i32x4 m4 = *(const i32x4*)(mrow + i * 16 + lg * 4);
    f32x4 sc = fz;
    sc = __builtin_amdgcn_mfma_f32_16x16x32_bf16(ka0, qf0, sc, 0, 0, 0);
    sc = __builtin_amdgcn_mfma_f32_16x16x32_bf16(ka1, qf1, sc, 0, 0, 0);
    const float e0 = __expf((m4[0] == 0) ? NEGV : sc[0] * scale);
    const float e1 = __expf((m4[1] == 0) ? NEGV : sc[1] * scale);
    const float e2 = __expf((m4[2] == 0) ? NEGV : sc[2] * scale);
    const float e3 = __expf((m4[3] == 0) ? NEGV : sc[3] * scale);
    rs += (e0 + e1) + (e2 + e3);
    pkA[i] = pack_bf2(e0, e1);
    pkB[i] = pack_bf2(e2, e3);
  }
  // per-wave row sum for q=lr (4 lanes with same lr hold partials)
  rs += __shfl_xor(rs, 16, 64);
  rs += __shfl_xor(rs, 32, 64);
  if (l < 16) rsred[w][l] = rs;
  __syncthreads();
  float ssum = 0.f;
#pragma unroll
  for (int ww = 0; ww < 8; ++ww) ssum += rsred[ww][lr];
  const float rinv = 1.0f / ssum;

  // ---- attn store (normalized) + PV on unnormalized P ----
  float* attnq = attnp + (size_t)((b * 16 + h) * S_LEN + q0 + lr) * S_LEN + kw0;
  const unsigned short* Vh = Vt + (size_t)(h * 64) * (2 * S_LEN) + (size_t)b * S_LEN + kw0;
  unsigned short* pbase = (unsigned short*)uni[w];

  f32x4 oacc[4];
#pragma unroll
  for (int n = 0; n < 4; ++n) oacc[n] = fz;

#pragma unroll
  for (int win = 0; win < 8; ++win) {
    const int wb = win * 32;
    const unsigned int a0 = pkA[2 * win],     a1 = pkB[2 * win];
    const unsigned int b0 = pkA[2 * win + 1], b1 = pkB[2 * win + 1];
    // normalized attn store (unpack bf16 halves + one mul each)
    const f32x4 st0 = {__uint_as_float(a0 << 16) * rinv,
                       __uint_as_float(a0 & 0xffff0000u) * rinv,
                       __uint_as_float(a1 << 16) * rinv,
                       __uint_as_float(a1 & 0xffff0000u) * rinv};
    const f32x4 st1 = {__uint_as_float(b0 << 16) * rinv,
                       __uint_as_float(b0 & 0xffff0000u) * rinv,
                       __uint_as_float(b1 << 16) * rinv,
                       __uint_as_float(b1 & 0xffff0000u) * rinv};
    __builtin_nontemporal_store(st0, (f32x4*)(attnq + wb + lg * 4));
    __builtin_nontemporal_store(st1, (f32x4*)(attnq + wb + 16 + lg * 4));

    // wave-private LDS repack: raw packed bf16 (zero VALU), double-buffered
    unsigned short* pb = pbase + (win & 1) * 640;
    const u32x2 wv0 = {a0, a1};
    const u32x2 wv1 = {b0, b1};
    *(u32x2*)(pb + lr * 40 + lg * 4) = wv0;
    *(u32x2*)(pb + lr * 40 + 16 + lg * 4) = wv1;
    const bf16x8 pa = *(const bf16x8*)(pb + lr * 40 + lg * 8);  // A[q=lr][k=lg*8..+7]

#pragma unroll
    for (int n = 0; n < 4; ++n) {
      const bf16x8 vb = *(const bf16x8*)(Vh + (size_t)(n * 16 + lr) * (2 * S_LEN) + wb + lg * 8);
      oacc[n] = __builtin_amdgcn_mfma_f32_16x16x32_bf16(pa, vb, oacc[n], 0, 0, 0);
    }
  }

  // ---- cross-wave out reduction (unnormalized; rinv applied per q-row here) ----
  asm volatile("s_waitcnt lgkmcnt(0)" ::: "memory");  // Pb reads done before outred overwrite
  float* outred = (float*)uni[w];
#pragma unroll
  for (int n = 0; n < 4; ++n)
#pragma unroll
    for (int jj = 0; jj < 4; ++jj)
      outred[(lg * 4 + jj) * 64 + n * 16 + lr] = oacc[n][jj];
  __syncthreads();
  if (threadIdx.x < 256) {
    const int q = threadIdx.x >> 4;
    const int d0 = (threadIdx.x & 15) * 4;
    float sq = 0.f;
#pragma unroll
    for (int ww = 0; ww < 8; ++ww) sq += rsred[ww][q];
    const float rq = 1.0f / sq;
    float4 o = {0.f, 0.f, 0.f, 0.f};
#pragma unroll
    for (int ww = 0; ww < 8; ++ww) {
      const f32x4 sv = *(const f32x4*)((const float*)uni[ww] + q * 64 + d0);
      o.x += sv[0]; o.y += sv[1]; o.z += sv[2]; o.w += sv[3];
    }
    o.x *= rq; o.y *= rq; o.z *= rq; o.w *= rq;
    *(float4*)(outp + (size_t)(b * S_LEN + q0 + q) * DM + h * 64 + d0) = o;
  }
}

extern "C" void kernel_launch(void* const* d_in, const int* in_sizes, int n_in,
                              void* d_out, int out_size, void* d_ws, size_t ws_size,
                              hipStream_t stream) {
  const float* query = (const float*)d_in[0];
  const float* key_  = (const float*)d_in[1];
  const float* value = (const float*)d_in[2];
  const int*   mask  = (const int*)d_in[3];
  const float* Wq = (const float*)d_in[4];
  const float* bq = (const float*)d_in[5];
  const float* Wk = (const float*)d_in[6];
  const float* bk = (const float*)d_in[7];
  const float* Wv = (const float*)d_in[8];
  const float* bv = (const float*)d_in[9];

  float* outp  = (float*)d_out;
  float* attnp = outp + (size_t)2 * S_LEN * DM;

  unsigned short* ws  = (unsigned short*)d_ws;
  unsigned short* qbf = ws;
  unsigned short* kbf = qbf + 4194304;
  unsigned short* vbf = kbf + 4194304;
  unsigned short* wqb = vbf + 4194304;
  unsigned short* wkb = wqb + 1048576;
  unsigned short* wvb = wkb + 1048576;
  unsigned short* qp  = wvb + 1048576;
  unsigned short* kp  = qp + 4194304;
  unsigned short* vp  = kp + 4194304;
  unsigned short* vt  = vp + 4194304;

  cvt_kernel<<<4096, 256, 0, stream>>>(query, qbf, 1048576);
  cvt_kernel<<<4096, 256, 0, stream>>>(key_,  kbf, 1048576);
  cvt_kernel<<<4096, 256, 0, stream>>>(value, vbf, 1048576);
  cvt_kernel<<<1024, 256, 0, stream>>>(Wq, wqb, 262144);
  cvt_kernel<<<1024, 256, 0, stream>>>(Wk, wkb, 262144);
  cvt_kernel<<<1024, 256, 0, stream>>>(Wv, wvb, 262144);

  proj_gemm<<<dim3(8, 32, 3), 256, 0, stream>>>(qbf, wqb, bq, qp,
                                                kbf, wkb, bk, kp,
                                                vbf, wvb, bv, vp);
  transpose_bf<<<dim3(32, 128), 256, 0, stream>>>(vp, vt);
  attn7_kernel<<<4096, 512, 0, stream>>>(qp, kp, vt, mask, outp, attnp);
}

// Round 9
// 401.866 us; speedup vs baseline: 2.5050x; 1.0422x over previous
//
#include <hip/hip_runtime.h>
#include <hip/hip_bf16.h>
#include <cstdint>
#include <cstddef>

#define S_LEN 2048
#define DM 1024
#define NEGV -1.0e9f

typedef __attribute__((ext_vector_type(8))) short bf16x8;
typedef __attribute__((ext_vector_type(4))) float f32x4;
typedef __attribute__((ext_vector_type(4))) unsigned short us4;
typedef __attribute__((ext_vector_type(4))) int i32x4;
typedef __attribute__((ext_vector_type(2))) unsigned int u32x2;

__device__ __forceinline__ unsigned short f2bf(float f) {
  unsigned int u = __float_as_uint(f);
  unsigned int r = (u + 0x7fffu + ((u >> 16) & 1u)) >> 16;
  return (unsigned short)r;
}

__device__ __forceinline__ unsigned int pack_bf2(float a, float b) {
  return (unsigned int)f2bf(a) | ((unsigned int)f2bf(b) << 16);
}

__device__ __forceinline__ void async_copy16(const void* g, void* l) {
  __builtin_amdgcn_global_load_lds((const __attribute__((address_space(1))) void*)g,
                                   (__attribute__((address_space(3))) void*)l, 16, 0, 0);
}

// ---------------- f32 -> bf16 convert ----------------
__global__ void cvt_kernel(const float* __restrict__ src, unsigned short* __restrict__ dst, int n4) {
  int i = blockIdx.x * blockDim.x + threadIdx.x;
  if (i >= n4) return;
  const float4 v = reinterpret_cast<const float4*>(src)[i];
  us4 o;
  o[0] = f2bf(v.x); o[1] = f2bf(v.y); o[2] = f2bf(v.z); o[3] = f2bf(v.w);
  reinterpret_cast<us4*>(dst)[i] = o;
}

// ---------------- projection GEMM (unchanged, passed) ----------------
__global__ __launch_bounds__(256) void proj_gemm(
    const unsigned short* __restrict__ Xq, const unsigned short* __restrict__ Wqw,
    const float* __restrict__ bq, unsigned short* __restrict__ Cq,
    const unsigned short* __restrict__ Xk, const unsigned short* __restrict__ Wkw,
    const float* __restrict__ bk, unsigned short* __restrict__ Ck,
    const unsigned short* __restrict__ Xv, const unsigned short* __restrict__ Wvw,
    const float* __restrict__ bv, unsigned short* __restrict__ Cv) {
  const unsigned short* X; const unsigned short* W; const float* bias; unsigned short* C;
  if (blockIdx.z == 0)      { X = Xq; W = Wqw; bias = bq; C = Cq; }
  else if (blockIdx.z == 1) { X = Xk; W = Wkw; bias = bk; C = Ck; }
  else                      { X = Xv; W = Wvw; bias = bv; C = Cv; }

  __shared__ unsigned short Ab[128 * 64];
  __shared__ unsigned short Bb[128 * 64];

  const int t  = threadIdx.x;
  const int wv = t >> 6, l = t & 63;
  const int lr = l & 15, lg = l >> 4;
  const int wr = wv >> 1, wc = wv & 1;
  const int m0 = blockIdx.y * 128, n0 = blockIdx.x * 128;

  const f32x4 fz = {0.f, 0.f, 0.f, 0.f};
  f32x4 acc[4][4];
#pragma unroll
  for (int m = 0; m < 4; ++m)
#pragma unroll
    for (int n = 0; n < 4; ++n) acc[m][n] = fz;

  const int srow = t >> 3;
  const int sc16 = t & 7;

  for (int kt = 0; kt < 16; ++kt) {
    const int kb = kt * 64;
#pragma unroll
    for (int it = 0; it < 4; ++it) {
      const int row = it * 32 + srow;
      const int c16 = sc16 ^ (row & 7);
      const unsigned short* gA = X + (size_t)(m0 + row) * DM + kb + c16 * 8;
      const unsigned short* gB = W + (size_t)(n0 + row) * DM + kb + c16 * 8;
      async_copy16(gA, (char*)Ab + it * 4096 + wv * 1024);
      async_copy16(gB, (char*)Bb + it * 4096 + wv * 1024);
    }
    __syncthreads();
#pragma unroll
    for (int kk = 0; kk < 2; ++kk) {
      bf16x8 af[4], bfr[4];
      const int c16 = kk * 4 + lg;
      const int sw = (c16 ^ (lr & 7)) * 16;
#pragma unroll
      for (int m = 0; m < 4; ++m) {
        const int row = wr * 64 + m * 16 + lr;
        af[m] = *(const bf16x8*)((const char*)Ab + row * 128 + sw);
      }
#pragma unroll
      for (int n = 0; n < 4; ++n) {
        const int row = wc * 64 + n * 16 + lr;
        bfr[n] = *(const bf16x8*)((const char*)Bb + row * 128 + sw);
      }
#pragma unroll
      for (int m = 0; m < 4; ++m)
#pragma unroll
        for (int n = 0; n < 4; ++n)
          acc[m][n] = __builtin_amdgcn_mfma_f32_16x16x32_bf16(af[m], bfr[n], acc[m][n], 0, 0, 0);
    }
    __syncthreads();
  }

#pragma unroll
  for (int n = 0; n < 4; ++n) {
    const int ccol = n0 + wc * 64 + n * 16 + lr;
    const float bb = bias[ccol];
#pragma unroll
    for (int m = 0; m < 4; ++m) {
      const int crow0 = m0 + wr * 64 + m * 16 + lg * 4;
#pragma unroll
      for (int j = 0; j < 4; ++j)
        C[(size_t)(crow0 + j) * DM + ccol] = f2bf(acc[m][n][j] + bb);
    }
  }
}

// ---------------- V transpose: [4096,1024] -> [1024,4096] ----------------
__global__ void transpose_bf(const unsigned short* __restrict__ src, unsigned short* __restrict__ dst) {
  __shared__ unsigned short tb[32][33];
  const int x = threadIdx.x & 31, y = threadIdx.x >> 5;
  const int bx = blockIdx.x, by = blockIdx.y;
#pragma unroll
  for (int r = 0; r < 32; r += 8)
    tb[r + y][x] = src[(size_t)(by * 32 + r + y) * DM + bx * 32 + x];
  __syncthreads();
#pragma unroll
  for (int r = 0; r < 32; r += 8)
    dst[(size_t)(bx * 32 + r + y) * 4096 + by * 32 + x] = tb[x][r + y];
}

// ---------------- fused attention v8: full-line coalesced attn stores ----------------
// vs v7: attn stores go through an LDS transpose so each store instruction writes
// 4 rows x 256 B contiguous segments (full 128-B lines), instead of 16 x 64-B
// partial-line NT writes (which bypass L2 write-combining). P staged per 64-key
// pair in a 16x66 LDS buffer (raw packed bf16, zero VALU); PV reads same buffer.
__global__ __launch_bounds__(512, 4) void attn8_kernel(
    const unsigned short* __restrict__ Qp, const unsigned short* __restrict__ Kp,
    const unsigned short* __restrict__ Vt, const int* __restrict__ mask,
    float* __restrict__ outp, float* __restrict__ attnp) {
  __shared__ float rsred[8][16];    // 512 B
  __shared__ float rinv16[16];      // 64 B
  __shared__ char uni[8][4224];     // 33 KB: per-wave 2x(16x66 sh) P buffers U outred (16x64 f32)

  const int bx = blockIdx.x;
  const int c  = bx & 7;            // XCD (round-robin dispatch)
  const int s  = bx >> 3;           // temporal order within XCD
  const int j  = s & 3;             // which of this XCD's 4 (b,h) pairs
  const int qt = s >> 2;            // 0..127, outer
  const int bh = c * 4 + j;
  const int b  = bh >> 4, h = bh & 15;
  const int q0 = qt << 4;

  const int w = threadIdx.x >> 6, l = threadIdx.x & 63;
  const int lr = l & 15, lg = l >> 4;
  const int kw0 = w << 8;           // 256 keys per wave

  const float scale = 0.125f;
  const f32x4 fz = {0.f, 0.f, 0.f, 0.f};

  // Q as B-operand: lane holds Q[q0+lr][lg*8..+7]
  const unsigned short* Qh = Qp + (size_t)(b * S_LEN + q0 + lr) * DM + h * 64;
  const bf16x8 qf0 = *(const bf16x8*)(Qh + lg * 8);
  const bf16x8 qf1 = *(const bf16x8*)(Qh + 32 + lg * 8);

  const unsigned short* Kh = Kp + (size_t)b * S_LEN * DM + h * 64 + (size_t)kw0 * DM;
  const int* mrow = mask + (size_t)(b * S_LEN + q0 + lr) * S_LEN + kw0;

  // ---- QK^T + mask + exp (one pass over K), packed bf16 in regs ----
  unsigned int pkA[16], pkB[16];
  float rs = 0.f;
#pragma unroll
  for (int i = 0; i < 16; ++i) {
    const unsigned short* Kr = Kh + (size_t)(i * 16 + lr) * DM;
    const bf16x8 ka0 = *(const bf16x8*)(Kr + lg * 8);
    const bf16x8 ka1 = *(const bf16x8*)(Kr + 32 + lg * 8);
    const i32x4 m4 = *(const i32x4*)(mrow + i * 16 + lg * 4);
    f32x4 sc = fz;
    sc = __builtin_amdgcn_mfma_f32_16x16x32_bf16(ka0, qf0, sc, 0, 0, 0);
    sc = __builtin_amdgcn_mfma_f32_16x16x32_bf16(ka1, qf1, sc, 0, 0, 0);
    const float e0 = __expf((m4[0] == 0) ? NEGV : sc[0] * scale);
    const float e1 = __expf((m4[1] == 0) ? NEGV : sc[1] * scale);
    const float e2 = __expf((m4[2] == 0) ? NEGV : sc[2] * scale);
    const float e3 = __expf((m4[3] == 0) ? NEGV : sc[3] * scale);
    rs += (e0 + e1) + (e2 + e3);
    pkA[i] = pack_bf2(e0, e1);
    pkB[i] = pack_bf2(e2, e3);
  }
  // per-wave row sum for q=lr (4 lanes with same lr hold partials)
  rs += __shfl_xor(rs, 16, 64);
  rs += __shfl_xor(rs, 32, 64);
  if (l < 16) rsred[w][l] = rs;
  __syncthreads();
  if (threadIdx.x < 16) {
    float s0 = 0.f;
#pragma unroll
    for (int ww = 0; ww < 8; ++ww) s0 += rsred[ww][threadIdx.x];
    rinv16[threadIdx.x] = 1.0f / s0;
  }
  __syncthreads();

  float rv4[4];
#pragma unroll
  for (int i = 0; i < 4; ++i) rv4[i] = rinv16[(l >> 4) + 4 * i];

  // ---- per-64-key pair: stage raw P in LDS -> coalesced stores + PV ----
  float* attnB = attnp + (size_t)((b * 16 + h) * S_LEN + q0) * S_LEN + kw0;
  const unsigned short* Vh = Vt + (size_t)(h * 64) * (2 * S_LEN) + (size_t)b * S_LEN + kw0;
  unsigned short* pbase = (unsigned short*)uni[w];

  f32x4 oacc[4];
#pragma unroll
  for (int n = 0; n < 4; ++n) oacc[n] = fz;

#pragma unroll
  for (int pr = 0; pr < 4; ++pr) {
    const int kb = pr * 64;
    unsigned short* pb = pbase + (pr & 1) * 1056;  // 16 rows x 66 sh, double-buffered
    // raw packed-bf16 P writes (both 32-key subchunks), zero VALU
#pragma unroll
    for (int s2 = 0; s2 < 2; ++s2) {
      const int wi = pr * 2 + s2;
      const u32x2 wv0 = {pkA[2 * wi],     pkB[2 * wi]};
      const u32x2 wv1 = {pkA[2 * wi + 1], pkB[2 * wi + 1]};
      *(u32x2*)(pb + lr * 66 + s2 * 32 + lg * 4) = wv0;
      *(u32x2*)(pb + lr * 66 + s2 * 32 + 16 + lg * 4) = wv1;
    }
    // coalesced attn stores: lane l -> row (l>>4)+4i, cols (l&15)*4..+3
    // each instr: 4 rows x 256 B contiguous (full lines)
#pragma unroll
    for (int i = 0; i < 4; ++i) {
      const int row = (l >> 4) + i * 4;
      const us4 p4 = *(const us4*)(pb + row * 66 + (l & 15) * 4);
      const float rv = rv4[i];
      const f32x4 st = {__uint_as_float((unsigned)p4[0] << 16) * rv,
                        __uint_as_float((unsigned)p4[1] << 16) * rv,
                        __uint_as_float((unsigned)p4[2] << 16) * rv,
                        __uint_as_float((unsigned)p4[3] << 16) * rv};
      __builtin_nontemporal_store(st, (f32x4*)(attnB + (size_t)row * S_LEN + kb + (l & 15) * 4));
    }
    // PV on unnormalized P (rinv folded into epilogue)
#pragma unroll
    for (int s2 = 0; s2 < 2; ++s2) {
      const bf16x8 pa = *(const bf16x8*)(pb + lr * 66 + s2 * 32 + lg * 8);
#pragma unroll
      for (int n = 0; n < 4; ++n) {
        const bf16x8 vb = *(const bf16x8*)(Vh + (size_t)(n * 16 + lr) * (2 * S_LEN) + kb + s2 * 32 + lg * 8);
        oacc[n] = __builtin_amdgcn_mfma_f32_16x16x32_bf16(pa, vb, oacc[n], 0, 0, 0);
      }
    }
  }

  // ---- cross-wave out reduction (unnormalized; rinv applied per q-row here) ----
  asm volatile("s_waitcnt lgkmcnt(0)" ::: "memory");  // P-buffer reads done before outred overwrite
  float* outred = (float*)uni[w];
#pragma unroll
  for (int n = 0; n < 4; ++n)
#pragma unroll
    for (int jj = 0; jj < 4; ++jj)
      outred[(lg * 4 + jj) * 64 + n * 16 + lr] = oacc[n][jj];
  __syncthreads();
  if (threadIdx.x < 256) {
    const int q = threadIdx.x >> 4;
    const int d0 = (threadIdx.x & 15) * 4;
    const float rq = rinv16[q];
    float4 o = {0.f, 0.f, 0.f, 0.f};
#pragma unroll
    for (int ww = 0; ww < 8; ++ww) {
      const f32x4 sv = *(const f32x4*)((const float*)uni[ww] + q * 64 + d0);
      o.x += sv[0]; o.y += sv[1]; o.z += sv[2]; o.w += sv[3];
    }
    o.x *= rq; o.y *= rq; o.z *= rq; o.w *= rq;
    *(float4*)(outp + (size_t)(b * S_LEN + q0 + q) * DM + h * 64 + d0) = o;
  }
}

extern "C" void kernel_launch(void* const* d_in, const int* in_sizes, int n_in,
                              void* d_out, int out_size, void* d_ws, size_t ws_size,
                              hipStream_t stream) {
  const float* query = (const float*)d_in[0];
  const float* key_  = (const float*)d_in[1];
  const float* value = (const float*)d_in[2];
  const int*   mask  = (const int*)d_in[3];
  const float* Wq = (const float*)d_in[4];
  const float* bq = (const float*)d_in[5];
  const float* Wk = (const float*)d_in[6];
  const float* bk = (const float*)d_in[7];
  const float* Wv = (const float*)d_in[8];
  const float* bv = (const float*)d_in[9];

  float* outp  = (float*)d_out;
  float* attnp = outp + (size_t)2 * S_LEN * DM;

  unsigned short* ws  = (unsigned short*)d_ws;
  unsigned short* qbf = ws;
  unsigned short* kbf = qbf + 4194304;
  unsigned short* vbf = kbf + 4194304;
  unsigned short* wqb = vbf + 4194304;
  unsigned short* wkb = wqb + 1048576;
  unsigned short* wvb = wkb + 1048576;
  unsigned short* qp  = wvb + 1048576;
  unsigned short* kp  = qp + 4194304;
  unsigned short* vp  = kp + 4194304;
  unsigned short* vt  = vp + 4194304;

  cvt_kernel<<<4096, 256, 0, stream>>>(query, qbf, 1048576);
  cvt_kernel<<<4096, 256, 0, stream>>>(key_,  kbf, 1048576);
  cvt_kernel<<<4096, 256, 0, stream>>>(value, vbf, 1048576);
  cvt_kernel<<<1024, 256, 0, stream>>>(Wq, wqb, 262144);
  cvt_kernel<<<1024, 256, 0, stream>>>(Wk, wkb, 262144);
  cvt_kernel<<<1024, 256, 0, stream>>>(Wv, wvb, 262144);

  proj_gemm<<<dim3(8, 32, 3), 256, 0, stream>>>(qbf, wqb, bq, qp,
                                                kbf, wkb, bk, kp,
                                                vbf, wvb, bv, vp);
  transpose_bf<<<dim3(32, 128), 256, 0, stream>>>(vp, vt);
  attn8_kernel<<<4096, 512, 0, stream>>>(qp, kp, vt, mask, outp, attnp);
}

// Round 10
// 345.168 us; speedup vs baseline: 2.9164x; 1.1643x over previous
//
#include <hip/hip_runtime.h>
#include <hip/hip_bf16.h>
#include <cstdint>
#include <cstddef>

#define S_LEN 2048
#define DM 1024
#define NEGV -1.0e9f

typedef __attribute__((ext_vector_type(8))) short bf16x8;
typedef __attribute__((ext_vector_type(4))) float f32x4;
typedef __attribute__((ext_vector_type(4))) unsigned short us4;
typedef __attribute__((ext_vector_type(4))) int i32x4;
typedef __attribute__((ext_vector_type(4))) unsigned int ui32x4;
typedef __attribute__((ext_vector_type(2))) unsigned int u32x2;

__device__ __forceinline__ unsigned short f2bf(float f) {
  unsigned int u = __float_as_uint(f);
  unsigned int r = (u + 0x7fffu + ((u >> 16) & 1u)) >> 16;
  return (unsigned short)r;
}

__device__ __forceinline__ unsigned int pack_bf2(float a, float b) {
  return (unsigned int)f2bf(a) | ((unsigned int)f2bf(b) << 16);
}

__device__ __forceinline__ void async_copy16(const void* g, void* l) {
  __builtin_amdgcn_global_load_lds((const __attribute__((address_space(1))) void*)g,
                                   (__attribute__((address_space(3))) void*)l, 16, 0, 0);
}

// ---------------- f32 -> bf16 convert ----------------
__global__ void cvt_kernel(const float* __restrict__ src, unsigned short* __restrict__ dst, int n4) {
  int i = blockIdx.x * blockDim.x + threadIdx.x;
  if (i >= n4) return;
  const float4 v = reinterpret_cast<const float4*>(src)[i];
  us4 o;
  o[0] = f2bf(v.x); o[1] = f2bf(v.y); o[2] = f2bf(v.z); o[3] = f2bf(v.w);
  reinterpret_cast<us4*>(dst)[i] = o;
}

// ---------------- mask int32 -> bitmask (33.5 MB -> 1 MB) ----------------
// thread = (row, word32): reads 32 ints, packs 32 bits. rows = B*S = 4096, words = 64.
__global__ __launch_bounds__(256) void maskbits_kernel(const int* __restrict__ mask,
                                                       unsigned int* __restrict__ mb) {
  const int idx = blockIdx.x * 256 + threadIdx.x;   // 262144 total
  const int row = idx >> 6, w = idx & 63;
  const int* src = mask + (size_t)row * S_LEN + w * 32;
  unsigned int r = 0;
#pragma unroll
  for (int j = 0; j < 8; ++j) {
    const i32x4 v = *(const i32x4*)(src + j * 4);
    r |= (v[0] ? 1u : 0u) << (j * 4 + 0);
    r |= (v[1] ? 1u : 0u) << (j * 4 + 1);
    r |= (v[2] ? 1u : 0u) << (j * 4 + 2);
    r |= (v[3] ? 1u : 0u) << (j * 4 + 3);
  }
  mb[(size_t)row * 64 + w] = r;
}

// ---------------- projection GEMM (unchanged, passed) ----------------
__global__ __launch_bounds__(256) void proj_gemm(
    const unsigned short* __restrict__ Xq, const unsigned short* __restrict__ Wqw,
    const float* __restrict__ bq, unsigned short* __restrict__ Cq,
    const unsigned short* __restrict__ Xk, const unsigned short* __restrict__ Wkw,
    const float* __restrict__ bk, unsigned short* __restrict__ Ck,
    const unsigned short* __restrict__ Xv, const unsigned short* __restrict__ Wvw,
    const float* __restrict__ bv, unsigned short* __restrict__ Cv) {
  const unsigned short* X; const unsigned short* W; const float* bias; unsigned short* C;
  if (blockIdx.z == 0)      { X = Xq; W = Wqw; bias = bq; C = Cq; }
  else if (blockIdx.z == 1) { X = Xk; W = Wkw; bias = bk; C = Ck; }
  else                      { X = Xv; W = Wvw; bias = bv; C = Cv; }

  __shared__ unsigned short Ab[128 * 64];
  __shared__ unsigned short Bb[128 * 64];

  const int t  = threadIdx.x;
  const int wv = t >> 6, l = t & 63;
  const int lr = l & 15, lg = l >> 4;
  const int wr = wv >> 1, wc = wv & 1;
  const int m0 = blockIdx.y * 128, n0 = blockIdx.x * 128;

  const f32x4 fz = {0.f, 0.f, 0.f, 0.f};
  f32x4 acc[4][4];
#pragma unroll
  for (int m = 0; m < 4; ++m)
#pragma unroll
    for (int n = 0; n < 4; ++n) acc[m][n] = fz;

  const int srow = t >> 3;
  const int sc16 = t & 7;

  for (int kt = 0; kt < 16; ++kt) {
    const int kb = kt * 64;
#pragma unroll
    for (int it = 0; it < 4; ++it) {
      const int row = it * 32 + srow;
      const int c16 = sc16 ^ (row & 7);
      const unsigned short* gA = X + (size_t)(m0 + row) * DM + kb + c16 * 8;
      const unsigned short* gB = W + (size_t)(n0 + row) * DM + kb + c16 * 8;
      async_copy16(gA, (char*)Ab + it * 4096 + wv * 1024);
      async_copy16(gB, (char*)Bb + it * 4096 + wv * 1024);
    }
    __syncthreads();
#pragma unroll
    for (int kk = 0; kk < 2; ++kk) {
      bf16x8 af[4], bfr[4];
      const int c16 = kk * 4 + lg;
      const int sw = (c16 ^ (lr & 7)) * 16;
#pragma unroll
      for (int m = 0; m < 4; ++m) {
        const int row = wr * 64 + m * 16 + lr;
        af[m] = *(const bf16x8*)((const char*)Ab + row * 128 + sw);
      }
#pragma unroll
      for (int n = 0; n < 4; ++n) {
        const int row = wc * 64 + n * 16 + lr;
        bfr[n] = *(const bf16x8*)((const char*)Bb + row * 128 + sw);
      }
#pragma unroll
      for (int m = 0; m < 4; ++m)
#pragma unroll
        for (int n = 0; n < 4; ++n)
          acc[m][n] = __builtin_amdgcn_mfma_f32_16x16x32_bf16(af[m], bfr[n], acc[m][n], 0, 0, 0);
    }
    __syncthreads();
  }

#pragma unroll
  for (int n = 0; n < 4; ++n) {
    const int ccol = n0 + wc * 64 + n * 16 + lr;
    const float bb = bias[ccol];
#pragma unroll
    for (int m = 0; m < 4; ++m) {
      const int crow0 = m0 + wr * 64 + m * 16 + lg * 4;
#pragma unroll
      for (int j = 0; j < 4; ++j)
        C[(size_t)(crow0 + j) * DM + ccol] = f2bf(acc[m][n][j] + bb);
    }
  }
}

// ---------------- V transpose: [4096,1024] -> [1024,4096] ----------------
__global__ void transpose_bf(const unsigned short* __restrict__ src, unsigned short* __restrict__ dst) {
  __shared__ unsigned short tb[32][33];
  const int x = threadIdx.x & 31, y = threadIdx.x >> 5;
  const int bx = blockIdx.x, by = blockIdx.y;
#pragma unroll
  for (int r = 0; r < 32; r += 8)
    tb[r + y][x] = src[(size_t)(by * 32 + r + y) * DM + bx * 32 + x];
  __syncthreads();
#pragma unroll
  for (int r = 0; r < 32; r += 8)
    dst[(size_t)(bx * 32 + r + y) * 4096 + by * 32 + x] = tb[x][r + y];
}

// ---------------- fused attention v9: register-resident bitmask, no mask loads in loop ----------------
// vs v8: (1) mask consumed as a precomputed bitmask loaded ONCE per lane (8 u32 regs,
// 1 MB total -> L2/L3 resident) — the per-iteration HBM mask load (the ~900-cy serial
// chain) is gone; (2) pass-2 issues V loads BEFORE the NT attn stores so the MFMA's
// vmcnt wait doesn't require store retirement (in-order counter).
__global__ __launch_bounds__(512, 4) void attn9_kernel(
    const unsigned short* __restrict__ Qp, const unsigned short* __restrict__ Kp,
    const unsigned short* __restrict__ Vt, const unsigned int* __restrict__ mbits,
    float* __restrict__ outp, float* __restrict__ attnp) {
  __shared__ float rsred[8][16];    // 512 B
  __shared__ float rinv16[16];      // 64 B
  __shared__ char uni[8][4224];     // 33 KB: per-wave 2x(16x66 sh) P buffers U outred (16x64 f32)

  const int bx = blockIdx.x;
  const int c  = bx & 7;            // XCD (round-robin dispatch)
  const int s  = bx >> 3;           // temporal order within XCD
  const int j  = s & 3;             // which of this XCD's 4 (b,h) pairs
  const int qt = s >> 2;            // 0..127, outer
  const int bh = c * 4 + j;
  const int b  = bh >> 4, h = bh & 15;
  const int q0 = qt << 4;

  const int w = threadIdx.x >> 6, l = threadIdx.x & 63;
  const int lr = l & 15, lg = l >> 4;
  const int kw0 = w << 8;           // 256 keys per wave

  const float scale = 0.125f;
  const f32x4 fz = {0.f, 0.f, 0.f, 0.f};

  // Q as B-operand: lane holds Q[q0+lr][lg*8..+7]
  const unsigned short* Qh = Qp + (size_t)(b * S_LEN + q0 + lr) * DM + h * 64;
  const bf16x8 qf0 = *(const bf16x8*)(Qh + lg * 8);
  const bf16x8 qf1 = *(const bf16x8*)(Qh + 32 + lg * 8);

  const unsigned short* Kh = Kp + (size_t)b * S_LEN * DM + h * 64 + (size_t)kw0 * DM;

  // bitmask slice for this lane's query row, this wave's 256 keys: 8 u32, loaded once
  const unsigned int* mbr = mbits + ((size_t)(b * S_LEN + q0 + lr) << 6) + (kw0 >> 5);
  const ui32x4 mwa = *(const ui32x4*)(mbr);
  const ui32x4 mwb = *(const ui32x4*)(mbr + 4);

  // ---- QK^T + bit-mask + exp (one pass over K), packed bf16 in regs ----
  unsigned int pkA[16], pkB[16];
  float rs = 0.f;
#pragma unroll
  for (int i = 0; i < 16; ++i) {
    const unsigned short* Kr = Kh + (size_t)(i * 16 + lr) * DM;
    const bf16x8 ka0 = *(const bf16x8*)(Kr + lg * 8);
    const bf16x8 ka1 = *(const bf16x8*)(Kr + 32 + lg * 8);
    f32x4 sc = fz;
    sc = __builtin_amdgcn_mfma_f32_16x16x32_bf16(ka0, qf0, sc, 0, 0, 0);
    sc = __builtin_amdgcn_mfma_f32_16x16x32_bf16(ka1, qf1, sc, 0, 0, 0);
    const unsigned int wsel = (i < 8) ? mwa[i >> 1] : mwb[(i - 8) >> 1];
    const unsigned int nib = (wsel >> ((i & 1) * 16 + lg * 4)) & 15u;
    const float e0 = __expf((nib & 1u) ? sc[0] * scale : NEGV);
    const float e1 = __expf((nib & 2u) ? sc[1] * scale : NEGV);
    const float e2 = __expf((nib & 4u) ? sc[2] * scale : NEGV);
    const float e3 = __expf((nib & 8u) ? sc[3] * scale : NEGV);
    rs += (e0 + e1) + (e2 + e3);
    pkA[i] = pack_bf2(e0, e1);
    pkB[i] = pack_bf2(e2, e3);
  }
  // per-wave row sum for q=lr (4 lanes with same lr hold partials)
  rs += __shfl_xor(rs, 16, 64);
  rs += __shfl_xor(rs, 32, 64);
  if (l < 16) rsred[w][l] = rs;
  __syncthreads();
  if (threadIdx.x < 16) {
    float s0 = 0.f;
#pragma unroll
    for (int ww = 0; ww < 8; ++ww) s0 += rsred[ww][threadIdx.x];
    rinv16[threadIdx.x] = 1.0f / s0;
  }
  __syncthreads();

  float rv4[4];
#pragma unroll
  for (int i = 0; i < 4; ++i) rv4[i] = rinv16[(l >> 4) + 4 * i];

  // ---- per-64-key pair: V loads first, then staged stores, then PV ----
  float* attnB = attnp + (size_t)((b * 16 + h) * S_LEN + q0) * S_LEN + kw0;
  const unsigned short* Vh = Vt + (size_t)(h * 64) * (2 * S_LEN) + (size_t)b * S_LEN + kw0;
  unsigned short* pbase = (unsigned short*)uni[w];

  f32x4 oacc[4];
#pragma unroll
  for (int n = 0; n < 4; ++n) oacc[n] = fz;

#pragma unroll
  for (int pr = 0; pr < 4; ++pr) {
    const int kb = pr * 64;
    unsigned short* pb = pbase + (pr & 1) * 1056;  // 16 rows x 66 sh, double-buffered

    // V loads issued FIRST (vmcnt decrements in issue order: MFMA's V-wait
    // completes without waiting on the stores issued after)
    bf16x8 vbr[2][4];
#pragma unroll
    for (int s2 = 0; s2 < 2; ++s2)
#pragma unroll
      for (int n = 0; n < 4; ++n)
        vbr[s2][n] = *(const bf16x8*)(Vh + (size_t)(n * 16 + lr) * (2 * S_LEN) + kb + s2 * 32 + lg * 8);

    // raw packed-bf16 P writes (both 32-key subchunks), zero VALU
#pragma unroll
    for (int s2 = 0; s2 < 2; ++s2) {
      const int wi = pr * 2 + s2;
      const u32x2 wv0 = {pkA[2 * wi],     pkB[2 * wi]};
      const u32x2 wv1 = {pkA[2 * wi + 1], pkB[2 * wi + 1]};
      *(u32x2*)(pb + lr * 66 + s2 * 32 + lg * 4) = wv0;
      *(u32x2*)(pb + lr * 66 + s2 * 32 + 16 + lg * 4) = wv1;
    }
    // coalesced attn stores: lane l -> row (l>>4)+4i, cols (l&15)*4..+3
#pragma unroll
    for (int i = 0; i < 4; ++i) {
      const int row = (l >> 4) + i * 4;
      const us4 p4 = *(const us4*)(pb + row * 66 + (l & 15) * 4);
      const float rv = rv4[i];
      const f32x4 st = {__uint_as_float((unsigned)p4[0] << 16) * rv,
                        __uint_as_float((unsigned)p4[1] << 16) * rv,
                        __uint_as_float((unsigned)p4[2] << 16) * rv,
                        __uint_as_float((unsigned)p4[3] << 16) * rv};
      __builtin_nontemporal_store(st, (f32x4*)(attnB + (size_t)row * S_LEN + kb + (l & 15) * 4));
    }
    // PV on unnormalized P (rinv folded into epilogue)
#pragma unroll
    for (int s2 = 0; s2 < 2; ++s2) {
      const bf16x8 pa = *(const bf16x8*)(pb + lr * 66 + s2 * 32 + lg * 8);
#pragma unroll
      for (int n = 0; n < 4; ++n)
        oacc[n] = __builtin_amdgcn_mfma_f32_16x16x32_bf16(pa, vbr[s2][n], oacc[n], 0, 0, 0);
    }
  }

  // ---- cross-wave out reduction (unnormalized; rinv applied per q-row here) ----
  asm volatile("s_waitcnt lgkmcnt(0)" ::: "memory");  // P-buffer reads done before outred overwrite
  float* outred = (float*)uni[w];
#pragma unroll
  for (int n = 0; n < 4; ++n)
#pragma unroll
    for (int jj = 0; jj < 4; ++jj)
      outred[(lg * 4 + jj) * 64 + n * 16 + lr] = oacc[n][jj];
  __syncthreads();
  if (threadIdx.x < 256) {
    const int q = threadIdx.x >> 4;
    const int d0 = (threadIdx.x & 15) * 4;
    const float rq = rinv16[q];
    float4 o = {0.f, 0.f, 0.f, 0.f};
#pragma unroll
    for (int ww = 0; ww < 8; ++ww) {
      const f32x4 sv = *(const f32x4*)((const float*)uni[ww] + q * 64 + d0);
      o.x += sv[0]; o.y += sv[1]; o.z += sv[2]; o.w += sv[3];
    }
    o.x *= rq; o.y *= rq; o.z *= rq; o.w *= rq;
    *(float4*)(outp + (size_t)(b * S_LEN + q0 + q) * DM + h * 64 + d0) = o;
  }
}

extern "C" void kernel_launch(void* const* d_in, const int* in_sizes, int n_in,
                              void* d_out, int out_size, void* d_ws, size_t ws_size,
                              hipStream_t stream) {
  const float* query = (const float*)d_in[0];
  const float* key_  = (const float*)d_in[1];
  const float* value = (const float*)d_in[2];
  const int*   mask  = (const int*)d_in[3];
  const float* Wq = (const float*)d_in[4];
  const float* bq = (const float*)d_in[5];
  const float* Wk = (const float*)d_in[6];
  const float* bk = (const float*)d_in[7];
  const float* Wv = (const float*)d_in[8];
  const float* bv = (const float*)d_in[9];

  float* outp  = (float*)d_out;
  float* attnp = outp + (size_t)2 * S_LEN * DM;

  unsigned short* ws  = (unsigned short*)d_ws;
  unsigned short* qbf = ws;
  unsigned short* kbf = qbf + 4194304;
  unsigned short* vbf = kbf + 4194304;
  unsigned short* wqb = vbf + 4194304;
  unsigned short* wkb = wqb + 1048576;
  unsigned short* wvb = wkb + 1048576;
  unsigned short* qp  = wvb + 1048576;
  unsigned short* kp  = qp + 4194304;
  unsigned short* vp  = kp + 4194304;
  unsigned short* vt  = vp + 4194304;
  unsigned int*   mb  = (unsigned int*)(vt + 4194304);   // 1 MB bitmask

  cvt_kernel<<<4096, 256, 0, stream>>>(query, qbf, 1048576);
  cvt_kernel<<<4096, 256, 0, stream>>>(key_,  kbf, 1048576);
  cvt_kernel<<<4096, 256, 0, stream>>>(value, vbf, 1048576);
  cvt_kernel<<<1024, 256, 0, stream>>>(Wq, wqb, 262144);
  cvt_kernel<<<1024, 256, 0, stream>>>(Wk, wkb, 262144);
  cvt_kernel<<<1024, 256, 0, stream>>>(Wv, wvb, 262144);
  maskbits_kernel<<<1024, 256, 0, stream>>>(mask, mb);

  proj_gemm<<<dim3(8, 32, 3), 256, 0, stream>>>(qbf, wqb, bq, qp,
                                                kbf, wkb, bk, kp,
                                                vbf, wvb, bv, vp);
  transpose_bf<<<dim3(32, 128), 256, 0, stream>>>(vp, vt);
  attn9_kernel<<<4096, 512, 0, stream>>>(qp, kp, vt, mb, outp, attnp);
}